// Round 1
// 463.282 us; speedup vs baseline: 1.0033x; 1.0033x over previous
//
#include <hip/hip_runtime.h>
#include <math.h>

// Problem constants (from reference): B=64, S=8192, D=64, fp32.
#define BB 64
#define SS 8192
#define DD 64

// Phase-1 S-chunks per batch: 8 x 64 batches = 512 blocks = 2 blocks/CU
constexpr int C1 = 8;
constexpr int CHUNK1 = SS / C1;       // 1024 s per block
constexpr int TILES1 = CHUNK1 / 64;   // 16 tiles of 64 s

typedef __attribute__((ext_vector_type(8))) short bf16x8;   // 8 bf16 = 4 VGPR (MFMA A/B frag)
typedef __attribute__((ext_vector_type(4))) float f32x4;    // MFMA C/D frag

__device__ __forceinline__ float fmap(float x) {
    // elu(x) + 1 == (x > 0 ? x + 1 : exp(x))
    return x > 0.0f ? x + 1.0f : __expf(x);
}

// float -> bf16 with round-to-nearest-even
__device__ __forceinline__ short f2bf(float x) {
    unsigned int u = __float_as_uint(x);
    u += 0x7FFFu + ((u >> 16) & 1u);
    return (short)(u >> 16);
}

// -------------------------------------------------------------------------
// Phase 1: kvT[b][e][d] = sum_s fmap(k[b][s][d]) * v[b][s][e]   (TRANSPOSED)
//          ksum[b][d]   = sum_s fmap(k[b][s][d])
// grid (C1, B), block 256 (4 waves).
// Each lane owns an 8x8 (d x e) register tile; the 4 waves split each
// 64-s tile 4-ways (16 s each) and cross-wave-reduce once at block end.
// Double-buffered LDS; global loads for tile t+1 issued before compute(t).
// -------------------------------------------------------------------------
__global__ __launch_bounds__(256) void phase1_kernel(
    const float* __restrict__ k,
    const float* __restrict__ v,
    float* __restrict__ kvT_ws,   // [B][D(e)][D(d)], pre-zeroed
    float* __restrict__ ksum_ws)  // [B][D],          pre-zeroed
{
    __shared__ float Ks[2][64 * 64];
    __shared__ float Vs[2][64 * 64];

    const int t    = threadIdx.x;
    const int lane = t & 63;
    const int w    = t >> 6;          // wave 0..3
    const int b    = blockIdx.y;
    const int schunk = blockIdx.x * CHUNK1;

    const float* kb = k + (size_t)b * SS * DD;
    const float* vb = v + (size_t)b * SS * DD;

    const int d0  = (lane >> 3) * 8;  // 8 d-rows owned by this lane
    const int e0  = (lane & 7) * 8;   // 8 e-cols owned by this lane
    const int sw0 = w * 16;           // wave's s-offset within each tile

    float acc[8][8] = {};
    float ksa[8] = {};

    // ---- prologue: stage tile 0 into buffer 0 ----
    {
        const float* kt = kb + (size_t)schunk * DD;
        const float* vt = vb + (size_t)schunk * DD;
        #pragma unroll
        for (int i = 0; i < 4; ++i) {
            const int idx = (t + i * 256) * 4;   // float index, 16B-aligned
            float4 kk = *(const float4*)(kt + idx);
            float4 vv = *(const float4*)(vt + idx);
            kk.x = fmap(kk.x); kk.y = fmap(kk.y);
            kk.z = fmap(kk.z); kk.w = fmap(kk.w);
            *(float4*)(&Ks[0][idx]) = kk;
            *(float4*)(&Vs[0][idx]) = vv;
        }
    }
    __syncthreads();

    for (int tile = 0; tile < TILES1; ++tile) {
        const int cur = tile & 1;
        float4 kreg[4], vreg[4];
        const bool pf = (tile < TILES1 - 1);
        if (pf) {
            // issue next tile's global loads BEFORE compute (latency hides under FMAs)
            const float* kt = kb + (size_t)(schunk + (tile + 1) * 64) * DD;
            const float* vt = vb + (size_t)(schunk + (tile + 1) * 64) * DD;
            #pragma unroll
            for (int i = 0; i < 4; ++i) {
                const int idx = (t + i * 256) * 4;
                kreg[i] = *(const float4*)(kt + idx);
                vreg[i] = *(const float4*)(vt + idx);
            }
        }
        // ---- compute on buffer cur: this wave's 16 s values ----
        const float* Kc = Ks[cur];
        const float* Vc = Vs[cur];
        #pragma unroll 4
        for (int s = 0; s < 16; ++s) {
            const float* krow = Kc + (sw0 + s) * 64;
            const float* vrow = Vc + (sw0 + s) * 64;
            float4 k0 = *(const float4*)(krow + d0);
            float4 k1 = *(const float4*)(krow + d0 + 4);
            float4 v0 = *(const float4*)(vrow + e0);
            float4 v1 = *(const float4*)(vrow + e0 + 4);
            const float kf[8] = {k0.x,k0.y,k0.z,k0.w,k1.x,k1.y,k1.z,k1.w};
            const float vv[8] = {v0.x,v0.y,v0.z,v0.w,v1.x,v1.y,v1.z,v1.w};
            #pragma unroll
            for (int i = 0; i < 8; ++i) {
                ksa[i] += kf[i];
                #pragma unroll
                for (int j = 0; j < 8; ++j) acc[i][j] += kf[i] * vv[j];
            }
        }
        if (pf) {
            // write prefetched tile into the other buffer (no hazard with cur)
            float* Kn = Ks[cur ^ 1];
            float* Vn = Vs[cur ^ 1];
            #pragma unroll
            for (int i = 0; i < 4; ++i) {
                const int idx = (t + i * 256) * 4;
                float4 kk = kreg[i];
                kk.x = fmap(kk.x); kk.y = fmap(kk.y);
                kk.z = fmap(kk.z); kk.w = fmap(kk.w);
                *(float4*)(&Kn[idx]) = kk;
                *(float4*)(&Vn[idx]) = vreg[i];
            }
        }
        __syncthreads();   // single barrier per tile
    }

    // ---- ksum commit: e-group-0 lanes of every wave hold distinct partials ----
    if ((lane & 7) == 0) {
        #pragma unroll
        for (int i = 0; i < 8; ++i)
            atomicAdd(ksum_ws + b * DD + d0 + i, ksa[i]);
    }

    // ---- cross-wave reduction of acc via LDS (reuse buffers as scratch) ----
    // round 1: w0 += w1 (via Ks[0]), w2 += w3 (via Vs[0]); round 2: w0 += w2.
    float* scr0 = &Ks[0][0];
    float* scr1 = &Vs[0][0];
    if (w & 1) {
        float* dst = (w == 1) ? scr0 : scr1;
        #pragma unroll
        for (int i = 0; i < 8; ++i)
            #pragma unroll
            for (int jj = 0; jj < 2; ++jj)
                *(float4*)(dst + (i * 2 + jj) * 256 + lane * 4) =
                    make_float4(acc[i][jj*4], acc[i][jj*4+1], acc[i][jj*4+2], acc[i][jj*4+3]);
    }
    __syncthreads();
    if (!(w & 1)) {
        const float* src = (w == 0) ? scr0 : scr1;
        #pragma unroll
        for (int i = 0; i < 8; ++i)
            #pragma unroll
            for (int jj = 0; jj < 2; ++jj) {
                float4 x = *(const float4*)(src + (i * 2 + jj) * 256 + lane * 4);
                acc[i][jj*4]   += x.x;
                acc[i][jj*4+1] += x.y;
                acc[i][jj*4+2] += x.z;
                acc[i][jj*4+3] += x.w;
            }
    }
    __syncthreads();
    if (w == 2) {
        #pragma unroll
        for (int i = 0; i < 8; ++i)
            #pragma unroll
            for (int jj = 0; jj < 2; ++jj)
                *(float4*)(scr0 + (i * 2 + jj) * 256 + lane * 4) =
                    make_float4(acc[i][jj*4], acc[i][jj*4+1], acc[i][jj*4+2], acc[i][jj*4+3]);
    }
    __syncthreads();
    if (w == 0) {
        #pragma unroll
        for (int i = 0; i < 8; ++i)
            #pragma unroll
            for (int jj = 0; jj < 2; ++jj) {
                float4 x = *(const float4*)(scr0 + (i * 2 + jj) * 256 + lane * 4);
                acc[i][jj*4]   += x.x;
                acc[i][jj*4+1] += x.y;
                acc[i][jj*4+2] += x.z;
                acc[i][jj*4+3] += x.w;
            }
        // commit TRANSPOSED: kvT[e][d]
        float* kvb = kvT_ws + (size_t)b * DD * DD;
        #pragma unroll
        for (int i = 0; i < 8; ++i)
            #pragma unroll
            for (int j = 0; j < 8; ++j)
                atomicAdd(kvb + (e0 + j) * DD + (d0 + i), acc[i][j]);
    }
}

// -------------------------------------------------------------------------
// Phase 2: o[b][s][e] = (sum_d qf[s][d] * kv[d][e]) / max(sum_d qf[s][d]*ksum[d], 1e-4)
// MFMA 16x16x32 bf16. No LDS, no barriers.
// grid (16, B), block 256: wave (blockIdx.x*4+w) owns 128 s-rows (8 16-row tiles).
// kv (as kvT[e][d]) is preloaded once into B-fragments (32 VGPR/lane);
// A-frags come straight from global q (2x dwordx4/lane, contiguous in d).
// Denominator kept in fp32 (per-lane partial dot + shfl reduce) for accuracy.
// -------------------------------------------------------------------------
__global__ __launch_bounds__(256) void phase2_kernel(
    const float* __restrict__ q,
    const float* __restrict__ kvT_ws,
    const float* __restrict__ ksum_ws,
    float* __restrict__ o)
{
    const int t    = threadIdx.x;
    const int lane = t & 63;
    const int w    = t >> 6;
    const int b    = blockIdx.y;
    const int wid  = blockIdx.x * 4 + w;   // 0..63
    const int g    = lane >> 4;            // k-group 0..3
    const int c    = lane & 15;            // A row / B col / D col

    // ---- preload kv B-fragments: B[k=d][n=e] from kvT[e][d] (contiguous d) ----
    const float* kvb = kvT_ws + (size_t)b * DD * DD;
    bf16x8 Bfrag[4][2];
    #pragma unroll
    for (int et = 0; et < 4; ++et) {
        #pragma unroll
        for (int dk = 0; dk < 2; ++dk) {
            const float* p = kvb + (et * 16 + c) * DD + dk * 32 + g * 8;
            float4 lo = *(const float4*)p;
            float4 hi = *(const float4*)(p + 4);
            bf16x8 f;
            f[0] = f2bf(lo.x); f[1] = f2bf(lo.y); f[2] = f2bf(lo.z); f[3] = f2bf(lo.w);
            f[4] = f2bf(hi.x); f[5] = f2bf(hi.y); f[6] = f2bf(hi.z); f[7] = f2bf(hi.w);
            Bfrag[et][dk] = f;
        }
    }
    // ksum (fp32) at the same per-lane d-indices as the A-fragment
    float ksr[16];
    #pragma unroll
    for (int dk = 0; dk < 2; ++dk) {
        const float* p = ksum_ws + b * DD + dk * 32 + g * 8;
        float4 lo = *(const float4*)p;
        float4 hi = *(const float4*)(p + 4);
        ksr[dk*8+0] = lo.x; ksr[dk*8+1] = lo.y; ksr[dk*8+2] = lo.z; ksr[dk*8+3] = lo.w;
        ksr[dk*8+4] = hi.x; ksr[dk*8+5] = hi.y; ksr[dk*8+6] = hi.z; ksr[dk*8+7] = hi.w;
    }

    const float* qb = q + (size_t)b * SS * DD;
    float*       ob = o + (size_t)b * SS * DD;

    #pragma unroll 1
    for (int tt = 0; tt < 8; ++tt) {
        const int s0 = wid * 128 + tt * 16;
        // ---- load + feature-map this lane's q fragment (row s0+c, d-chunks) ----
        const float* qrow = qb + (size_t)(s0 + c) * DD;
        float qf[16];
        #pragma unroll
        for (int dk = 0; dk < 2; ++dk) {
            float4 lo = *(const float4*)(qrow + dk * 32 + g * 8);
            float4 hi = *(const float4*)(qrow + dk * 32 + g * 8 + 4);
            qf[dk*8+0] = fmap(lo.x); qf[dk*8+1] = fmap(lo.y);
            qf[dk*8+2] = fmap(lo.z); qf[dk*8+3] = fmap(lo.w);
            qf[dk*8+4] = fmap(hi.x); qf[dk*8+5] = fmap(hi.y);
            qf[dk*8+6] = fmap(hi.z); qf[dk*8+7] = fmap(hi.w);
        }
        // ---- denominator in fp32: partial dot + reduce over the 4 k-groups ----
        float dn = 0.0f;
        #pragma unroll
        for (int i = 0; i < 16; ++i) dn += qf[i] * ksr[i];
        dn += __shfl_xor(dn, 16, 64);
        dn += __shfl_xor(dn, 32, 64);   // now dn = deno for row (s0 + c), on all lanes

        // ---- pack A-fragments (bf16) ----
        bf16x8 A0, A1;
        #pragma unroll
        for (int i = 0; i < 8; ++i) { A0[i] = f2bf(qf[i]); A1[i] = f2bf(qf[8+i]); }

        // ---- MFMA: 4 e-tiles x 2 k-chunks ----
        f32x4 acc0 = {0.f,0.f,0.f,0.f}, acc1 = {0.f,0.f,0.f,0.f};
        f32x4 acc2 = {0.f,0.f,0.f,0.f}, acc3 = {0.f,0.f,0.f,0.f};
        acc0 = __builtin_amdgcn_mfma_f32_16x16x32_bf16(A0, Bfrag[0][0], acc0, 0, 0, 0);
        acc0 = __builtin_amdgcn_mfma_f32_16x16x32_bf16(A1, Bfrag[0][1], acc0, 0, 0, 0);
        acc1 = __builtin_amdgcn_mfma_f32_16x16x32_bf16(A0, Bfrag[1][0], acc1, 0, 0, 0);
        acc1 = __builtin_amdgcn_mfma_f32_16x16x32_bf16(A1, Bfrag[1][1], acc1, 0, 0, 0);
        acc2 = __builtin_amdgcn_mfma_f32_16x16x32_bf16(A0, Bfrag[2][0], acc2, 0, 0, 0);
        acc2 = __builtin_amdgcn_mfma_f32_16x16x32_bf16(A1, Bfrag[2][1], acc2, 0, 0, 0);
        acc3 = __builtin_amdgcn_mfma_f32_16x16x32_bf16(A0, Bfrag[3][0], acc3, 0, 0, 0);
        acc3 = __builtin_amdgcn_mfma_f32_16x16x32_bf16(A1, Bfrag[3][1], acc3, 0, 0, 0);

        // ---- epilogue: D[row=4g+r][col=c]; fetch deno for row 4g+r from lane (4g+r) ----
        #pragma unroll
        for (int r = 0; r < 4; ++r) {
            float dr  = __shfl(dn, (g << 2) + r, 64);
            float inv = 1.0f / fmaxf(dr, 1e-4f);
            float* op = ob + (size_t)(s0 + (g << 2) + r) * DD + c;
            op[0]  = acc0[r] * inv;
            op[16] = acc1[r] * inv;
            op[32] = acc2[r] * inv;
            op[48] = acc3[r] * inv;
        }
    }
}

extern "C" void kernel_launch(void* const* d_in, const int* in_sizes, int n_in,
                              void* d_out, int out_size, void* d_ws, size_t ws_size,
                              hipStream_t stream) {
    const float* q = (const float*)d_in[0];
    const float* k = (const float*)d_in[1];
    const float* v = (const float*)d_in[2];
    float* o = (float*)d_out;

    float* kvT_ws  = (float*)d_ws;                       // B*D*D floats, [b][e][d]
    float* ksum_ws = kvT_ws + (size_t)BB * DD * DD;      // B*D floats
    const size_t ws_bytes = ((size_t)BB * DD * DD + (size_t)BB * DD) * sizeof(float);

    // Workspace is re-poisoned before every timed launch -> zero it.
    hipMemsetAsync(d_ws, 0, ws_bytes, stream);

    dim3 g1(C1, BB), g2(16, BB), blk(256);
    phase1_kernel<<<g1, blk, 0, stream>>>(k, v, kvT_ws, ksum_ws);
    phase2_kernel<<<g2, blk, 0, stream>>>(q, kvT_ws, ksum_ws, o);
}

// Round 3
// 416.268 us; speedup vs baseline: 1.1166x; 1.1129x over previous
//
#include <hip/hip_runtime.h>
#include <math.h>

// Problem constants (from reference): B=64, S=8192, D=64, fp32.
#define BB 64
#define SS 8192
#define DD 64

// Phase-1: 8 s-chunks x 64 batches = 512 blocks (1 block/CU resident, 2 rounds)
constexpr int C1 = 8;
constexpr int CHUNK1 = SS / C1;          // 1024 s per block
constexpr int TROWS  = 128;              // s-rows per LDS tile (4 K-steps of 32)
constexpr int TILES1 = CHUNK1 / TROWS;   // 8 tiles

typedef __attribute__((ext_vector_type(8))) short bf16x8;   // MFMA A/B frag (4 VGPR)
typedef __attribute__((ext_vector_type(4))) float f32x4;    // MFMA C/D frag

__device__ __forceinline__ float fmap(float x) {
    // elu(x) + 1 == (x > 0 ? x + 1 : exp(x))
    return x > 0.0f ? x + 1.0f : __expf(x);
}

// float -> bf16 round-to-nearest-even
__device__ __forceinline__ short f2bf(float x) {
    unsigned int u = __float_as_uint(x);
    u += 0x7FFFu + ((u >> 16) & 1u);
    return (short)(u >> 16);
}

// split fp32 -> (hi = bf16 truncation, lo = bf16 RNE of exact residue)
// x ~= hi + lo with |err| ~ 2^-17 |x|; products compensated via hh+hl+lh.
__device__ __forceinline__ void split8(const float* x, bf16x8& hi, bf16x8& lo) {
    #pragma unroll
    for (int i = 0; i < 8; ++i) {
        unsigned int u = __float_as_uint(x[i]);
        hi[i] = (short)(u >> 16);                          // truncate = exact bf16 head
        float l = x[i] - __uint_as_float(u & 0xFFFF0000u); // exact residue in fp32
        lo[i] = f2bf(l);
    }
}

__device__ __forceinline__ void gload_lds16(const float* gsrc, float* ldst) {
    __builtin_amdgcn_global_load_lds(
        (const __attribute__((address_space(1))) unsigned int*)gsrc,
        (__attribute__((address_space(3))) unsigned int*)ldst,
        16, 0, 0);
}

// -------------------------------------------------------------------------
// Phase 1 (MFMA): kvT[b][e][d] = sum_s v[b][s][e] * fmap(k[b][s][d])
//                 ksum[b][d]   = sum_s fmap(k[b][s][d])
// A = v^T (m=e, k=s), B = fmap(k) (k=s, n=d)  ->  D[e][d] = kvT directly.
// Both operands hi/lo-split (3 MFMA terms) for near-fp32 accuracy.
// LDS: fp32 tiles [128][64], double-buffered, staged via global_load_lds
// width=16 with a 16B-chunk XOR swizzle (ch ^= ((s>>3)&1)<<2) pre-applied to
// the GLOBAL source address so stride-256B fragment gathers are <=2-way
// bank aliased (free). One barrier per tile.
// grid (C1, B), block 256 (4 waves; wave w owns K-step rows w*32..w*32+31).
// -------------------------------------------------------------------------
__global__ __launch_bounds__(256) void phase1_kernel(
    const float* __restrict__ k,
    const float* __restrict__ v,
    float* __restrict__ kvT_ws,   // [B][D(e)][D(d)], pre-zeroed
    float* __restrict__ ksum_ws)  // [B][D],          pre-zeroed
{
    __shared__ float Ks[2][TROWS * 64];   // 2 x 32 KiB
    __shared__ float Vs[2][TROWS * 64];   // 2 x 32 KiB   (total 128 KiB)

    const int t    = threadIdx.x;
    const int lane = t & 63;
    const int w    = t >> 6;          // wave 0..3
    const int g    = lane >> 4;       // k-group 0..3
    const int c    = lane & 15;       // frag row/col
    const int b    = blockIdx.y;

    const size_t base = (size_t)b * SS * DD + (size_t)blockIdx.x * CHUNK1 * DD;
    const float* kb = k + base;
    const float* vb = v + base;

    // stage one 128x64 fp32 tile of each matrix into buf (16B-chunk pre-swizzled src)
    auto issue_tile = [&](int tt, int buf) {
        const float* kt = kb + tt * (TROWS * 64);
        const float* vt = vb + tt * (TROWS * 64);
        #pragma unroll
        for (int i = 0; i < 8; ++i) {
            const int Lidx = (w * 8 + i) * 64 + lane;   // 16B-chunk linear index
            const int s    = Lidx >> 4;                 // tile row
            const int p    = Lidx & 15;                 // stored chunk pos
            const int gch  = p ^ (((s >> 3) & 1) << 2); // global chunk (XOR involution)
            const int goff = s * 64 + gch * 4;          // float offset
            const int loff = (w * 8 + i) * 256;         // lane-0 LDS float offset
            gload_lds16(kt + goff, &Ks[buf][loff]);
            gload_lds16(vt + goff, &Vs[buf][loff]);
        }
    };

    f32x4 acc[4][4] = {};   // [et][dt] -> D rows e=et*16+4g+r, cols d=dt*16+c
    float ksa[4] = {};

    issue_tile(0, 0);
    __syncthreads();   // vmcnt(0) drained by compiler before barrier

    for (int tt = 0; tt < TILES1; ++tt) {
        const int cur = tt & 1;
        if (tt + 1 < TILES1) issue_tile(tt + 1, cur ^ 1);

        const float* Kc = Ks[cur];
        const float* Vc = Vs[cur];
        const int srow = w * 32 + g * 8;       // this lane's first k-row (K-step = wave id)
        const int sw   = (g & 1) << 2;         // swizzle key, constant over i (s>>3 fixed)

        // ---- A-frags from V (no fmap), hi/lo split ----
        bf16x8 Ah[4], Al[4];
        #pragma unroll
        for (int et = 0; et < 4; ++et) {
            const int dc   = et * 16 + c;      // e-coordinate
            const int bidx = srow * 64 + ((((dc >> 2) ^ sw)) << 2) + (dc & 3);
            float x[8];
            #pragma unroll
            for (int i = 0; i < 8; ++i) x[i] = Vc[bidx + i * 64];
            split8(x, Ah[et], Al[et]);
        }
        // ---- B-frags from K (fmap'd), hi/lo split; MFMA; ksum ----
        #pragma unroll
        for (int dt = 0; dt < 4; ++dt) {
            const int dc   = dt * 16 + c;      // d-coordinate
            const int bidx = srow * 64 + ((((dc >> 2) ^ sw)) << 2) + (dc & 3);
            float y[8];
            #pragma unroll
            for (int i = 0; i < 8; ++i) y[i] = fmap(Kc[bidx + i * 64]);
            ksa[dt] += ((y[0] + y[1]) + (y[2] + y[3])) + ((y[4] + y[5]) + (y[6] + y[7]));
            bf16x8 Bh, Bl;
            split8(y, Bh, Bl);
            #pragma unroll
            for (int et = 0; et < 4; ++et) {
                acc[et][dt] = __builtin_amdgcn_mfma_f32_16x16x32_bf16(Ah[et], Bh, acc[et][dt], 0, 0, 0);
                acc[et][dt] = __builtin_amdgcn_mfma_f32_16x16x32_bf16(Ah[et], Bl, acc[et][dt], 0, 0, 0);
                acc[et][dt] = __builtin_amdgcn_mfma_f32_16x16x32_bf16(Al[et], Bh, acc[et][dt], 0, 0, 0);
            }
        }
        __syncthreads();   // readers done + next tile's loads landed
    }

    // ---- ksum: reduce over the 4 k-groups, then one atomic per (dt, c) ----
    #pragma unroll
    for (int dt = 0; dt < 4; ++dt) {
        float s = ksa[dt];
        s += __shfl_xor(s, 16, 64);
        s += __shfl_xor(s, 32, 64);
        ksa[dt] = s;
    }
    if (lane < 16) {
        #pragma unroll
        for (int dt = 0; dt < 4; ++dt)
            atomicAdd(ksum_ws + b * DD + dt * 16 + lane, ksa[dt]);
    }

    // ---- kv commit: per-wave [e][d] scratch in LDS, then coalesced atomics ----
    float* scr = &Ks[0][0] + w * 4096;   // 4 x 16 KiB spans Ks[0..1]
    #pragma unroll
    for (int et = 0; et < 4; ++et)
        #pragma unroll
        for (int dt = 0; dt < 4; ++dt)
            #pragma unroll
            for (int r = 0; r < 4; ++r) {
                const int e = et * 16 + 4 * g + r;
                const int d = dt * 16 + c;
                scr[e * 64 + d] = acc[et][dt][r];
            }
    __syncthreads();
    float* kvb = kvT_ws + (size_t)b * DD * DD;
    const float* s0 = &Ks[0][0];
    #pragma unroll
    for (int jj = 0; jj < 16; ++jj) {
        const int i = jj * 256 + t;   // lane-consecutive -> coalesced LDS + atomics
        const float vsum = (s0[i] + s0[4096 + i]) + (s0[8192 + i] + s0[12288 + i]);
        atomicAdd(kvb + i, vsum);
    }
}

// -------------------------------------------------------------------------
// Phase 2: o[b][s][e] = (sum_d qf[s][d] * kv[d][e]) / max(sum_d qf[s][d]*ksum[d], 1e-4)
// MFMA 16x16x32 bf16. No LDS, no barriers. (unchanged from round 1)
// -------------------------------------------------------------------------
__global__ __launch_bounds__(256) void phase2_kernel(
    const float* __restrict__ q,
    const float* __restrict__ kvT_ws,
    const float* __restrict__ ksum_ws,
    float* __restrict__ o)
{
    const int t    = threadIdx.x;
    const int lane = t & 63;
    const int w    = t >> 6;
    const int b    = blockIdx.y;
    const int wid  = blockIdx.x * 4 + w;   // 0..63
    const int g    = lane >> 4;            // k-group 0..3
    const int c    = lane & 15;            // A row / B col / D col

    // ---- preload kv B-fragments: B[k=d][n=e] from kvT[e][d] (contiguous d) ----
    const float* kvb = kvT_ws + (size_t)b * DD * DD;
    bf16x8 Bfrag[4][2];
    #pragma unroll
    for (int et = 0; et < 4; ++et) {
        #pragma unroll
        for (int dk = 0; dk < 2; ++dk) {
            const float* p = kvb + (et * 16 + c) * DD + dk * 32 + g * 8;
            float4 lo = *(const float4*)p;
            float4 hi = *(const float4*)(p + 4);
            bf16x8 f;
            f[0] = f2bf(lo.x); f[1] = f2bf(lo.y); f[2] = f2bf(lo.z); f[3] = f2bf(lo.w);
            f[4] = f2bf(hi.x); f[5] = f2bf(hi.y); f[6] = f2bf(hi.z); f[7] = f2bf(hi.w);
            Bfrag[et][dk] = f;
        }
    }
    // ksum (fp32) at the same per-lane d-indices as the A-fragment
    float ksr[16];
    #pragma unroll
    for (int dk = 0; dk < 2; ++dk) {
        const float* p = ksum_ws + b * DD + dk * 32 + g * 8;
        float4 lo = *(const float4*)p;
        float4 hi = *(const float4*)(p + 4);
        ksr[dk*8+0] = lo.x; ksr[dk*8+1] = lo.y; ksr[dk*8+2] = lo.z; ksr[dk*8+3] = lo.w;
        ksr[dk*8+4] = hi.x; ksr[dk*8+5] = hi.y; ksr[dk*8+6] = hi.z; ksr[dk*8+7] = hi.w;
    }

    const float* qb = q + (size_t)b * SS * DD;
    float*       ob = o + (size_t)b * SS * DD;

    #pragma unroll 1
    for (int tt = 0; tt < 8; ++tt) {
        const int s0 = wid * 128 + tt * 16;
        const float* qrow = qb + (size_t)(s0 + c) * DD;
        float qf[16];
        #pragma unroll
        for (int dk = 0; dk < 2; ++dk) {
            float4 lo = *(const float4*)(qrow + dk * 32 + g * 8);
            float4 hi = *(const float4*)(qrow + dk * 32 + g * 8 + 4);
            qf[dk*8+0] = fmap(lo.x); qf[dk*8+1] = fmap(lo.y);
            qf[dk*8+2] = fmap(lo.z); qf[dk*8+3] = fmap(lo.w);
            qf[dk*8+4] = fmap(hi.x); qf[dk*8+5] = fmap(hi.y);
            qf[dk*8+6] = fmap(hi.z); qf[dk*8+7] = fmap(hi.w);
        }
        // ---- denominator in fp32: partial dot + reduce over the 4 k-groups ----
        float dn = 0.0f;
        #pragma unroll
        for (int i = 0; i < 16; ++i) dn += qf[i] * ksr[i];
        dn += __shfl_xor(dn, 16, 64);
        dn += __shfl_xor(dn, 32, 64);   // dn = deno for row (s0 + c), on all lanes

        // ---- pack A-fragments (bf16) ----
        bf16x8 A0, A1;
        #pragma unroll
        for (int i = 0; i < 8; ++i) { A0[i] = f2bf(qf[i]); A1[i] = f2bf(qf[8+i]); }

        // ---- MFMA: 4 e-tiles x 2 k-chunks ----
        f32x4 acc0 = {0.f,0.f,0.f,0.f}, acc1 = {0.f,0.f,0.f,0.f};
        f32x4 acc2 = {0.f,0.f,0.f,0.f}, acc3 = {0.f,0.f,0.f,0.f};
        acc0 = __builtin_amdgcn_mfma_f32_16x16x32_bf16(A0, Bfrag[0][0], acc0, 0, 0, 0);
        acc0 = __builtin_amdgcn_mfma_f32_16x16x32_bf16(A1, Bfrag[0][1], acc0, 0, 0, 0);
        acc1 = __builtin_amdgcn_mfma_f32_16x16x32_bf16(A0, Bfrag[1][0], acc1, 0, 0, 0);
        acc1 = __builtin_amdgcn_mfma_f32_16x16x32_bf16(A1, Bfrag[1][1], acc1, 0, 0, 0);
        acc2 = __builtin_amdgcn_mfma_f32_16x16x32_bf16(A0, Bfrag[2][0], acc2, 0, 0, 0);
        acc2 = __builtin_amdgcn_mfma_f32_16x16x32_bf16(A1, Bfrag[2][1], acc2, 0, 0, 0);
        acc3 = __builtin_amdgcn_mfma_f32_16x16x32_bf16(A0, Bfrag[3][0], acc3, 0, 0, 0);
        acc3 = __builtin_amdgcn_mfma_f32_16x16x32_bf16(A1, Bfrag[3][1], acc3, 0, 0, 0);

        // ---- epilogue: D[row=4g+r][col=c]; deno for row 4g+r from lane (4g+r) ----
        #pragma unroll
        for (int r = 0; r < 4; ++r) {
            float dr  = __shfl(dn, (g << 2) + r, 64);
            float inv = 1.0f / fmaxf(dr, 1e-4f);
            float* op = ob + (size_t)(s0 + (g << 2) + r) * DD + c;
            op[0]  = acc0[r] * inv;
            op[16] = acc1[r] * inv;
            op[32] = acc2[r] * inv;
            op[48] = acc3[r] * inv;
        }
    }
}

extern "C" void kernel_launch(void* const* d_in, const int* in_sizes, int n_in,
                              void* d_out, int out_size, void* d_ws, size_t ws_size,
                              hipStream_t stream) {
    const float* q = (const float*)d_in[0];
    const float* k = (const float*)d_in[1];
    const float* v = (const float*)d_in[2];
    float* o = (float*)d_out;

    float* kvT_ws  = (float*)d_ws;                       // B*D*D floats, [b][e][d]
    float* ksum_ws = kvT_ws + (size_t)BB * DD * DD;      // B*D floats
    const size_t ws_bytes = ((size_t)BB * DD * DD + (size_t)BB * DD) * sizeof(float);

    // Workspace is re-poisoned before every timed launch -> zero it.
    hipMemsetAsync(d_ws, 0, ws_bytes, stream);

    dim3 g1(C1, BB), g2(16, BB), blk(256);
    phase1_kernel<<<g1, blk, 0, stream>>>(k, v, kvT_ws, ksum_ws);
    phase2_kernel<<<g2, blk, 0, stream>>>(q, kvT_ws, ksum_ws, o);
}

// Round 4
// 407.739 us; speedup vs baseline: 1.1399x; 1.0209x over previous
//
#include <hip/hip_runtime.h>
#include <math.h>

// Problem constants (from reference): B=64, S=8192, D=64, fp32.
#define BB 64
#define SS 8192
#define DD 64

// Phase-1: 8 s-chunks x 64 batches = 512 blocks; 64 KiB LDS -> 2 blocks/CU
// resident => all 512 co-resident, 8 waves/CU (2/SIMD).
constexpr int C1 = 8;
constexpr int CHUNK1 = SS / C1;          // 1024 s per block
constexpr int TROWS  = 64;               // s-rows per LDS tile (2 K-steps of 32)
constexpr int TILES1 = CHUNK1 / TROWS;   // 16 tiles

typedef __attribute__((ext_vector_type(8))) short bf16x8;   // MFMA A/B frag (4 VGPR)
typedef __attribute__((ext_vector_type(4))) float f32x4;    // MFMA C/D frag

__device__ __forceinline__ float fmap(float x) {
    // elu(x) + 1 == (x > 0 ? x + 1 : exp(x))
    return x > 0.0f ? x + 1.0f : __expf(x);
}

// float -> bf16 round-to-nearest-even
__device__ __forceinline__ short f2bf(float x) {
    unsigned int u = __float_as_uint(x);
    u += 0x7FFFu + ((u >> 16) & 1u);
    return (short)(u >> 16);
}

// split fp32 -> (hi = bf16 truncation, lo = bf16 RNE of exact residue)
// x ~= hi + lo with |err| ~ 2^-17 |x|; products compensated via hh+hl+lh.
__device__ __forceinline__ void split8(const float* x, bf16x8& hi, bf16x8& lo) {
    #pragma unroll
    for (int i = 0; i < 8; ++i) {
        unsigned int u = __float_as_uint(x[i]);
        hi[i] = (short)(u >> 16);                          // truncate = exact bf16 head
        float l = x[i] - __uint_as_float(u & 0xFFFF0000u); // exact residue in fp32
        lo[i] = f2bf(l);
    }
}

__device__ __forceinline__ void gload_lds16(const float* gsrc, float* ldst) {
    __builtin_amdgcn_global_load_lds(
        (const __attribute__((address_space(1))) unsigned int*)gsrc,
        (__attribute__((address_space(3))) unsigned int*)ldst,
        16, 0, 0);
}

// -------------------------------------------------------------------------
// Phase 1 (MFMA): kvT[b][e][d] = sum_s v[b][s][e] * fmap(k[b][s][d])
//                 ksum[b][d]   = sum_s fmap(k[b][s][d])
// A = v^T (m=e, k=s), B = fmap(k) (k=s, n=d)  ->  D[e][d] = kvT directly.
// Both operands hi/lo-split (3 MFMA terms) for near-fp32 accuracy.
// Tile 64x64 fp32, double-buffered (64 KiB LDS total -> 2 blocks/CU).
// Wave split: step = w&1 owns K-rows step*32..+32; dh = w>>1 owns output
// columns dh*32..+32. 96 wave-MFMA/tile = exact work, no redundancy.
// Staged via global_load_lds width=16 with 16B-chunk XOR swizzle
// (ch ^= ((s>>3)&1)<<2) pre-applied to the GLOBAL source so stride-256B
// fragment gathers are <=2-way bank aliased (free). One barrier per tile.
// -------------------------------------------------------------------------
__global__ __launch_bounds__(256) void phase1_kernel(
    const float* __restrict__ k,
    const float* __restrict__ v,
    float* __restrict__ kvT_ws,   // [B][D(e)][D(d)], pre-zeroed
    float* __restrict__ ksum_ws)  // [B][D],          pre-zeroed
{
    __shared__ float Ks[2][TROWS * 64];   // 2 x 16 KiB
    __shared__ float Vs[2][TROWS * 64];   // 2 x 16 KiB   (total 64 KiB)

    const int t    = threadIdx.x;
    const int lane = t & 63;
    const int w    = t >> 6;          // wave 0..3
    const int g    = lane >> 4;       // k-group 0..3
    const int c    = lane & 15;       // frag row/col
    const int b    = blockIdx.y;
    const int step = w & 1;           // which K=32 slab of the tile
    const int dh   = w >> 1;          // which 32-column output half

    const size_t base = (size_t)b * SS * DD + (size_t)blockIdx.x * CHUNK1 * DD;
    const float* kb = k + base;
    const float* vb = v + base;

    // stage one 64x64 fp32 tile of each matrix into buf (16B-chunk pre-swizzled src)
    auto issue_tile = [&](int tt, int buf) {
        const float* kt = kb + tt * (TROWS * 64);
        const float* vt = vb + tt * (TROWS * 64);
        #pragma unroll
        for (int i = 0; i < 4; ++i) {
            const int Lidx = i * 256 + t;               // 16B-chunk linear index 0..1023
            const int s    = Lidx >> 4;                 // tile row
            const int p    = Lidx & 15;                 // stored chunk pos
            const int gch  = p ^ (((s >> 3) & 1) << 2); // global chunk (XOR involution)
            const int goff = s * 64 + gch * 4;          // float offset in tile
            const int loff = (i * 256 + w * 64) * 4;    // wave-uniform LDS float offset
            gload_lds16(kt + goff, &Ks[buf][loff]);
            gload_lds16(vt + goff, &Vs[buf][loff]);
        }
    };

    f32x4 acc[4][2] = {};   // [et][j] -> D rows e=et*16+4g+r, cols d=(dh*2+j)*16+c
    float ksa[2] = {};

    issue_tile(0, 0);
    __syncthreads();   // vmcnt(0) drained by compiler before barrier

    for (int tt = 0; tt < TILES1; ++tt) {
        const int cur = tt & 1;
        if (tt + 1 < TILES1) issue_tile(tt + 1, cur ^ 1);

        const float* Kc = Ks[cur];
        const float* Vc = Vs[cur];
        const int srow = step * 32 + g * 8;    // lane's first k-row in the tile
        const int sw   = (g & 1) << 2;         // swizzle key ((s>>3)&1 == g&1 here)

        // ---- A-frags from V (no fmap), hi/lo split; all 4 e-tiles ----
        bf16x8 Ah[4], Al[4];
        #pragma unroll
        for (int et = 0; et < 4; ++et) {
            const int dc   = et * 16 + c;      // e-coordinate
            const int bidx = srow * 64 + (((dc >> 2) ^ sw) << 2) + (dc & 3);
            float x[8];
            #pragma unroll
            for (int i = 0; i < 8; ++i) x[i] = Vc[bidx + i * 64];
            split8(x, Ah[et], Al[et]);
        }
        // ---- B-frags from K (fmap'd), this wave's 2 d-tiles; MFMA; ksum ----
        #pragma unroll
        for (int j = 0; j < 2; ++j) {
            const int dc   = (dh * 2 + j) * 16 + c;    // d-coordinate
            const int bidx = srow * 64 + (((dc >> 2) ^ sw) << 2) + (dc & 3);
            float y[8];
            #pragma unroll
            for (int i = 0; i < 8; ++i) y[i] = fmap(Kc[bidx + i * 64]);
            ksa[j] += ((y[0] + y[1]) + (y[2] + y[3])) + ((y[4] + y[5]) + (y[6] + y[7]));
            bf16x8 Bh, Bl;
            split8(y, Bh, Bl);
            #pragma unroll
            for (int et = 0; et < 4; ++et) {
                acc[et][j] = __builtin_amdgcn_mfma_f32_16x16x32_bf16(Ah[et], Bh, acc[et][j], 0, 0, 0);
                acc[et][j] = __builtin_amdgcn_mfma_f32_16x16x32_bf16(Ah[et], Bl, acc[et][j], 0, 0, 0);
                acc[et][j] = __builtin_amdgcn_mfma_f32_16x16x32_bf16(Al[et], Bh, acc[et][j], 0, 0, 0);
            }
        }
        __syncthreads();   // readers done + next tile's loads landed
    }

    // ---- ksum: reduce over the 4 k-groups (rows), one atomic per column ----
    #pragma unroll
    for (int j = 0; j < 2; ++j) {
        float s = ksa[j];
        s += __shfl_xor(s, 16, 64);
        s += __shfl_xor(s, 32, 64);
        ksa[j] = s;
    }
    if (lane < 16) {
        #pragma unroll
        for (int j = 0; j < 2; ++j)
            atomicAdd(ksum_ws + b * DD + (dh * 2 + j) * 16 + lane, ksa[j]);
    }

    // ---- cross-wave pair reduction: wave(step1,dh) -> wave(step0,dh) ----
    // odd waves dump acc into Ks[0] scratch (2048 floats each), even waves add.
    {
        float* scr = &Ks[0][0] + dh * 2048;
        if (step == 1) {
            #pragma unroll
            for (int et = 0; et < 4; ++et)
                #pragma unroll
                for (int j = 0; j < 2; ++j)
                    #pragma unroll
                    for (int r = 0; r < 4; ++r)
                        scr[((et * 2 + j) * 4 + r) * 64 + lane] = acc[et][j][r];
        }
    }
    __syncthreads();
    if (step == 0) {
        const float* scr = &Ks[0][0] + dh * 2048;
        float* cscr = &Vs[0][0];   // commit scratch arranged [e][d], 64x64
        #pragma unroll
        for (int et = 0; et < 4; ++et)
            #pragma unroll
            for (int j = 0; j < 2; ++j)
                #pragma unroll
                for (int r = 0; r < 4; ++r) {
                    const float s = acc[et][j][r] + scr[((et * 2 + j) * 4 + r) * 64 + lane];
                    const int e = et * 16 + 4 * g + r;
                    const int d = (dh * 2 + j) * 16 + c;
                    cscr[e * 64 + d] = s;
                }
    }
    __syncthreads();
    // ---- coalesced atomic commit from Vs[0] ----
    float* kvb = kvT_ws + (size_t)b * DD * DD;
    const float* cscr = &Vs[0][0];
    #pragma unroll
    for (int jj = 0; jj < 16; ++jj) {
        const int i = jj * 256 + t;   // lane-consecutive -> coalesced
        atomicAdd(kvb + i, cscr[i]);
    }
}

// -------------------------------------------------------------------------
// Phase 2: o[b][s][e] = (sum_d qf[s][d] * kv[d][e]) / max(sum_d qf[s][d]*ksum[d], 1e-4)
// MFMA 16x16x32 bf16. No LDS, no barriers. Software-pipelined q loads:
// tile tt+1's four float4 are issued before computing tile tt.
// grid (16, B), block 256: wave (blockIdx.x*4+w) owns 128 s-rows (8 16-row tiles).
// -------------------------------------------------------------------------
__global__ __launch_bounds__(256) void phase2_kernel(
    const float* __restrict__ q,
    const float* __restrict__ kvT_ws,
    const float* __restrict__ ksum_ws,
    float* __restrict__ o)
{
    const int t    = threadIdx.x;
    const int lane = t & 63;
    const int w    = t >> 6;
    const int b    = blockIdx.y;
    const int wid  = blockIdx.x * 4 + w;   // 0..63
    const int g    = lane >> 4;            // k-group 0..3
    const int c    = lane & 15;            // A row / B col / D col

    // ---- preload kv B-fragments: B[k=d][n=e] from kvT[e][d] (contiguous d) ----
    const float* kvb = kvT_ws + (size_t)b * DD * DD;
    bf16x8 Bfrag[4][2];
    #pragma unroll
    for (int et = 0; et < 4; ++et) {
        #pragma unroll
        for (int dk = 0; dk < 2; ++dk) {
            const float* p = kvb + (et * 16 + c) * DD + dk * 32 + g * 8;
            float4 lo = *(const float4*)p;
            float4 hi = *(const float4*)(p + 4);
            bf16x8 f;
            f[0] = f2bf(lo.x); f[1] = f2bf(lo.y); f[2] = f2bf(lo.z); f[3] = f2bf(lo.w);
            f[4] = f2bf(hi.x); f[5] = f2bf(hi.y); f[6] = f2bf(hi.z); f[7] = f2bf(hi.w);
            Bfrag[et][dk] = f;
        }
    }
    // ksum (fp32) at the same per-lane d-indices as the A-fragment
    float ksr[16];
    #pragma unroll
    for (int dk = 0; dk < 2; ++dk) {
        const float* p = ksum_ws + b * DD + dk * 32 + g * 8;
        float4 lo = *(const float4*)p;
        float4 hi = *(const float4*)(p + 4);
        ksr[dk*8+0] = lo.x; ksr[dk*8+1] = lo.y; ksr[dk*8+2] = lo.z; ksr[dk*8+3] = lo.w;
        ksr[dk*8+4] = hi.x; ksr[dk*8+5] = hi.y; ksr[dk*8+6] = hi.z; ksr[dk*8+7] = hi.w;
    }

    const float* qb = q + (size_t)b * SS * DD;
    float*       ob = o + (size_t)b * SS * DD;

    // prefetch registers for the software pipeline
    const float* qrow = qb + (size_t)(wid * 128 + c) * DD;
    float4 p0 = *(const float4*)(qrow + g * 8);
    float4 p1 = *(const float4*)(qrow + g * 8 + 4);
    float4 p2 = *(const float4*)(qrow + 32 + g * 8);
    float4 p3 = *(const float4*)(qrow + 32 + g * 8 + 4);

    #pragma unroll 1
    for (int tt = 0; tt < 8; ++tt) {
        const int s0 = wid * 128 + tt * 16;
        float4 c0 = p0, c1 = p1, c2 = p2, c3 = p3;
        if (tt < 7) {   // issue next tile's loads before computing current
            const float* qn = qb + (size_t)(s0 + 16 + c) * DD;
            p0 = *(const float4*)(qn + g * 8);
            p1 = *(const float4*)(qn + g * 8 + 4);
            p2 = *(const float4*)(qn + 32 + g * 8);
            p3 = *(const float4*)(qn + 32 + g * 8 + 4);
        }
        float qf[16];
        qf[0]  = fmap(c0.x); qf[1]  = fmap(c0.y); qf[2]  = fmap(c0.z); qf[3]  = fmap(c0.w);
        qf[4]  = fmap(c1.x); qf[5]  = fmap(c1.y); qf[6]  = fmap(c1.z); qf[7]  = fmap(c1.w);
        qf[8]  = fmap(c2.x); qf[9]  = fmap(c2.y); qf[10] = fmap(c2.z); qf[11] = fmap(c2.w);
        qf[12] = fmap(c3.x); qf[13] = fmap(c3.y); qf[14] = fmap(c3.z); qf[15] = fmap(c3.w);

        // ---- denominator in fp32: partial dot + reduce over the 4 k-groups ----
        float dn = 0.0f;
        #pragma unroll
        for (int i = 0; i < 16; ++i) dn += qf[i] * ksr[i];
        dn += __shfl_xor(dn, 16, 64);
        dn += __shfl_xor(dn, 32, 64);   // dn = deno for row (s0 + c), on all lanes

        // ---- pack A-fragments (bf16) ----
        bf16x8 A0, A1;
        #pragma unroll
        for (int i = 0; i < 8; ++i) { A0[i] = f2bf(qf[i]); A1[i] = f2bf(qf[8+i]); }

        // ---- MFMA: 4 e-tiles x 2 k-chunks ----
        f32x4 acc0 = {0.f,0.f,0.f,0.f}, acc1 = {0.f,0.f,0.f,0.f};
        f32x4 acc2 = {0.f,0.f,0.f,0.f}, acc3 = {0.f,0.f,0.f,0.f};
        acc0 = __builtin_amdgcn_mfma_f32_16x16x32_bf16(A0, Bfrag[0][0], acc0, 0, 0, 0);
        acc0 = __builtin_amdgcn_mfma_f32_16x16x32_bf16(A1, Bfrag[0][1], acc0, 0, 0, 0);
        acc1 = __builtin_amdgcn_mfma_f32_16x16x32_bf16(A0, Bfrag[1][0], acc1, 0, 0, 0);
        acc1 = __builtin_amdgcn_mfma_f32_16x16x32_bf16(A1, Bfrag[1][1], acc1, 0, 0, 0);
        acc2 = __builtin_amdgcn_mfma_f32_16x16x32_bf16(A0, Bfrag[2][0], acc2, 0, 0, 0);
        acc2 = __builtin_amdgcn_mfma_f32_16x16x32_bf16(A1, Bfrag[2][1], acc2, 0, 0, 0);
        acc3 = __builtin_amdgcn_mfma_f32_16x16x32_bf16(A0, Bfrag[3][0], acc3, 0, 0, 0);
        acc3 = __builtin_amdgcn_mfma_f32_16x16x32_bf16(A1, Bfrag[3][1], acc3, 0, 0, 0);

        // ---- epilogue: D[row=4g+r][col=c]; deno for row 4g+r from lane (4g+r) ----
        #pragma unroll
        for (int r = 0; r < 4; ++r) {
            float dr  = __shfl(dn, (g << 2) + r, 64);
            float inv = 1.0f / fmaxf(dr, 1e-4f);
            float* op = ob + (size_t)(s0 + (g << 2) + r) * DD + c;
            op[0]  = acc0[r] * inv;
            op[16] = acc1[r] * inv;
            op[32] = acc2[r] * inv;
            op[48] = acc3[r] * inv;
        }
    }
}

extern "C" void kernel_launch(void* const* d_in, const int* in_sizes, int n_in,
                              void* d_out, int out_size, void* d_ws, size_t ws_size,
                              hipStream_t stream) {
    const float* q = (const float*)d_in[0];
    const float* k = (const float*)d_in[1];
    const float* v = (const float*)d_in[2];
    float* o = (float*)d_out;

    float* kvT_ws  = (float*)d_ws;                       // B*D*D floats, [b][e][d]
    float* ksum_ws = kvT_ws + (size_t)BB * DD * DD;      // B*D floats
    const size_t ws_bytes = ((size_t)BB * DD * DD + (size_t)BB * DD) * sizeof(float);

    // Workspace is re-poisoned before every timed launch -> zero it.
    hipMemsetAsync(d_ws, 0, ws_bytes, stream);

    dim3 g1(C1, BB), g2(16, BB), blk(256);
    phase1_kernel<<<g1, blk, 0, stream>>>(k, v, kvT_ws, ksum_ws);
    phase2_kernel<<<g2, blk, 0, stream>>>(q, kvT_ws, ksum_ws, o);
}